// Round 2
// baseline (131.014 us; speedup 1.0000x reference)
//
#include <hip/hip_runtime.h>
#include <hip/hip_fp16.h>
#include <math.h>

// AFM forward, pipelined-staging v2: ISO-OCCUPANCY discriminator.
// Round-1 (SPW=2, 256-thr blocks) was neutral vs baseline, but it confounded
// the pipelining gain with an occupancy drop (grid 1024 -> 4 blocks/CU vs
// baseline 5). This version keeps SPW=2 cross-sample gather/compute overlap
// AND restores 20 waves/CU: 128-thread blocks (2 waves) x SPW=2 -> grid 2048,
// launch_bounds(128,5) = 10 blocks/CU. To fit the ~96-VGPR cap at 5 waves/EU,
// the 24-entry pair-offset table moves from registers to a per-block LDS
// table [NT][32] (conflict-free lane-contiguous reads, compile-time tile
// offset, prefetched 2 tiles ahead), freeing ~20 VGPRs for ~1 ds_read_b32
// per tile. Table is filled redundantly by each wave (benign identical-value
// race) -> still zero barriers.
//
// Discriminates: latency/flood-bound (expect kernel ~31.7 -> ~24us) vs
// HBM-random-gather-BW-bound (expect neutral -> declare roofline next).
//
// Session laws preserved: (1) >=96 VGPR budget respected by design (po table
// evicted); (2) exactly ONE inlined tile-loop instance (sample loop unroll 1).

#define BB 8192
#define FF 39
#define PP 741
#define NT 24                  // 32-pair tiles per sample; tile 23 has 5 valid
#define RBYTES 48              // fp16 row stride: 32B data + 16B pad
#define SBYTES (FF * RBYTES)   // 1872 B fp16 region per wave
#define STGB   (FF * 64)       // 2496 B f32 staging region per wave
#define CH     (FF * 4)        // 156 16B chunks per sample
#define SPW    2               // samples per wave (sequential, pipelined)
#define WLDS   (STGB + SBYTES) // 4368 B per wave
#define POB    (NT * 32 * 4)   // 3072 B pair-offset table per block

typedef _Float16 f16x8 __attribute__((ext_vector_type(8)));
typedef _Float16 h2    __attribute__((ext_vector_type(2)));
typedef __fp16   hw2   __attribute__((ext_vector_type(2)));  // builtin ABI type
typedef float    f32x4  __attribute__((ext_vector_type(4)));
typedef float    f32x16 __attribute__((ext_vector_type(16)));

// static pair table, transposed: v[n][k] = byte offsets of pair p = k*32+n,
// packed (i*RBYTES)<<16 | (j*RBYTES). Dead slots (p>=741) stay 0 (masked).
struct alignas(16) PijT { unsigned v[32][NT]; };
static constexpr PijT make_pij() {
    PijT t{};
    int p = 0;
    for (int i = 0; i < FF; ++i)
        for (int j = i + 1; j < FF; ++j) {
            t.v[p & 31][p >> 5] =
                ((unsigned)(i * RBYTES) << 16) | (unsigned)(j * RBYTES);
            ++p;
        }
    return t;
}
__device__ constexpr PijT c_pij = make_pij();

static __device__ __forceinline__ h2 cvt2(float lo, float hi) {
    return __builtin_bit_cast(h2, __builtin_amdgcn_cvt_pkrtz(lo, hi));
}
static __device__ __forceinline__ h2 ash2(unsigned d) {
    return __builtin_bit_cast(h2, d);
}
static __device__ __forceinline__ float fdot2f(h2 a, h2 b, float c) {
    return __builtin_amdgcn_fdot2(__builtin_bit_cast(hw2, a),
                                  __builtin_bit_cast(hw2, b), c, false);
}
static __device__ __forceinline__ h2 relu2(h2 x) {
    const h2 zz = {(_Float16)0.f, (_Float16)0.f};
    return __builtin_elementwise_max(x, zz);   // v_pk_max_f16
}

// async 16B global->LDS DMA (per-lane global addr, LDS dest = base + lane*16)
static __device__ __forceinline__ void gld_lds16(const void* g, void* l) {
    __builtin_amdgcn_global_load_lds(
        (const __attribute__((address_space(1))) void*)g,
        (__attribute__((address_space(3))) void*)l, 16, 0, 0);
}

__global__ __launch_bounds__(128, 5)
void afm_kernel(const int*   __restrict__ fidx,
                const float* __restrict__ fval,
                const float* __restrict__ fow,
                const float* __restrict__ emb,
                const float* __restrict__ bias,
                const float* __restrict__ aw_,   // [E=16][A=16] row-major
                const float* __restrict__ ab_,   // [16]
                const float* __restrict__ ph_,   // [16]
                const float* __restrict__ pp_,   // [16]
                float*       __restrict__ out)
{
    __shared__ __align__(16) unsigned char s_all[POB + 2 * WLDS];  // 11808 B

    const int tid  = threadIdx.x;
    const int wid  = tid >> 6;
    const int lane = tid & 63;
    const int n    = lane & 31;      // pair slot within tile
    const int h    = lane >> 5;      // e-half / k-half
    const int s0   = (blockIdx.x * 2 + wid) * SPW;

    unsigned*      po_lds = (unsigned*)s_all;          // [NT][32], t-major
    unsigned char* stg = s_all + POB + wid * WLDS;     // f32 staging (DMA dest)
    unsigned char* my  = stg + STGB;                   // fp16 scaled rows

    // ---- (0) pair table -> LDS. Each wave writes the WHOLE table (identical
    //          values; benign race) so same-wave LDS ordering suffices. ------
    #pragma unroll
    for (int u = lane; u < NT * 32; u += 64)
        po_lds[u] = c_pij.v[u & 31][u >> 5];   // po_lds[t][n] layout

    // ---- (1) per-field idx/val for BOTH samples (issue these loads first) --
    int idxA = 0, idxB = 0; float vA = 0.f, vB = 0.f;
    if (lane < FF) {
        idxA = fidx[s0 * FF + lane];
        vA   = fval[s0 * FF + lane];
        idxB = fidx[(s0 + 1) * FF + lane];
        vB   = fval[(s0 + 1) * FF + lane];
    }

    // ---- (2) constant-fragment raw loads --------------------------------
    const float LOG2E = 1.44269504088896f;
    const f32x4 ph_lo = ((const f32x4*)ph_)[h];
    const f32x4 ph_hi = ((const f32x4*)ph_)[h + 2];
    const f32x4 ab_lo = ((const f32x4*)ab_)[h];
    const f32x4 ab_hi = ((const f32x4*)ab_)[h + 2];
    float t0 = 0.f, t1 = 0.f, t2 = 0.f, t3 = 0.f,
          t4 = 0.f, t5 = 0.f, t6 = 0.f, t7 = 0.f;
    if (n < 16) {
        const float* base = aw_ + (8 * h) * 16 + n;  // W[k=8h+j][m=n]
        t0 = base[0];   t1 = base[16];  t2 = base[32];  t3 = base[48];
        t4 = base[64];  t5 = base[80];  t6 = base[96];  t7 = base[112];
    } else if (n == 16) {
        const float* base = pp_ + 8 * h;             // p[k=8h+j]
        t0 = base[0]; t1 = base[1]; t2 = base[2]; t3 = base[3];
        t4 = base[4]; t5 = base[5]; t6 = base[6]; t7 = base[7];
    }

    // ---- (3) first-order gathers (used only at the final reduce) ---------
    float foA = (lane < FF) ? fow[idxA] : 0.f;
    float foB = (lane < FF) ? fow[idxB] : 0.f;

    // ---- (4) chunk embedding indices via shfl; issue DMA for sample A ----
    // chunk u = 64k+lane covers row u>>2, quarter u&3 of that row (16B each).
    const int r0 = lane >> 2, r1 = (64 + lane) >> 2, r2 = (128 + lane) >> 2;
    const int cA0 = __shfl(idxA, r0), cA1 = __shfl(idxA, r1),
              cA2 = __shfl(idxA, r2);
    const int cB0 = __shfl(idxB, r0), cB1 = __shfl(idxB, r1),
              cB2 = __shfl(idxB, r2);
    const int q4 = (lane & 3) * 4;

    gld_lds16(emb + (size_t)(unsigned)cA0 * 16 + q4, stg);
    gld_lds16(emb + (size_t)(unsigned)cA1 * 16 + q4, stg + 1024);
    if (lane < CH - 128)
        gld_lds16(emb + (size_t)(unsigned)cA2 * 16 + q4, stg + 2048);

    // ---- (5) frag ARITHMETIC (VALU-only; overlaps sample-A DMA latency) --
    h2 hp0 = cvt2(ph_lo[0] * LOG2E, ph_lo[1] * LOG2E);
    h2 hp1 = cvt2(ph_lo[2] * LOG2E, ph_lo[3] * LOG2E);
    h2 hp2 = cvt2(ph_hi[0] * LOG2E, ph_hi[1] * LOG2E);
    h2 hp3 = cvt2(ph_hi[2] * LOG2E, ph_hi[3] * LOG2E);

    f32x16 cinit;                   // bias in rows a<16; rows >=16 zero
    cinit[0] = ab_lo[0]; cinit[1] = ab_lo[1];
    cinit[2] = ab_lo[2]; cinit[3] = ab_lo[3];
    cinit[4] = ab_hi[0]; cinit[5] = ab_hi[1];
    cinit[6] = ab_hi[2]; cinit[7] = ab_hi[3];
    #pragma unroll
    for (int r = 8; r < 16; ++r) cinit[r] = 0.f;

    f16x8 wfrag;        // A: rows 0..15 = W^T, row 16 = proj_p, 17..31 zero
    {
        union { h2 hh[4]; f16x8 v; } u;
        u.hh[0] = cvt2(t0, t1); u.hh[1] = cvt2(t2, t3);
        u.hh[2] = cvt2(t4, t5); u.hh[3] = cvt2(t6, t7);
        wfrag = u.v;
    }

    const unsigned char* bpre = my + h * 16;    // this lane's e-half

    // ---- (6) sample loop: cvt staged rows -> fp16, issue next DMA, compute
    float vcur = vA, vnxt = vB;
    float fcur = foA, fnxt = foB;

    #pragma unroll 1
    for (int s = 0; s < SPW; ++s) {
        // DMA for sample s complete (also drains older loads; fine)
        asm volatile("s_waitcnt vmcnt(0)" ::: "memory");
        __builtin_amdgcn_sched_barrier(0);

        // cvt pass: linear conflict-free b128 reads, scale, fp16 b64 writes
        #pragma unroll
        for (int k = 0; k < 3; ++k) {
            const int u   = 64 * k + lane;
            const int row = u >> 2, q = u & 3;
            const float v = __shfl(vcur, row);   // all lanes active here
            if (u < CH) {
                const f32x4 e = *(const f32x4*)(stg + u * 16);
                h2 a0 = cvt2(e[0] * v, e[1] * v);
                h2 a1 = cvt2(e[2] * v, e[3] * v);
                uint2 dd = make_uint2(__builtin_bit_cast(unsigned, a0),
                                      __builtin_bit_cast(unsigned, a1));
                *(uint2*)(my + row * RBYTES + q * 8) = dd;
            }
        }

        // stage-buffer reads retired before the DMA engine may overwrite it
        asm volatile("s_waitcnt lgkmcnt(0)" ::: "memory");
        __builtin_amdgcn_sched_barrier(0);

        if (s == 0) {   // issue sample-B gathers; they fly under the main loop
            gld_lds16(emb + (size_t)(unsigned)cB0 * 16 + q4, stg);
            gld_lds16(emb + (size_t)(unsigned)cB1 * 16 + q4, stg + 1024);
            if (lane < CH - 128)
                gld_lds16(emb + (size_t)(unsigned)cB2 * 16 + q4, stg + 2048);
        }

        // ---- main loop: 24 tiles; di/dj prefetch 1 ahead, po 2 ahead ------
        float aw = 0.f;                             // sum_p w_p * (bi_p . p)
        float z  = 0.f;                             // sum_p w_p (x2 halves)

        unsigned po0 = po_lds[n];                   // tile 0 offsets
        unsigned pon = po_lds[32 + n];              // tile 1 offsets
        uint4 di = *(const uint4*)(bpre + (po0 >> 16));
        uint4 dj = *(const uint4*)(bpre + (po0 & 0xFFFFu));

        #pragma unroll
        for (int t = 0; t < NT; ++t) {
            unsigned pon2 = 0;
            if (t + 2 < NT)                          // compile-time offset
                pon2 = po_lds[(t + 2) * 32 + n];
            uint4 diN = di, djN = dj;
            if (t + 1 < NT) {
                diN = *(const uint4*)(bpre + (pon >> 16));
                djN = *(const uint4*)(bpre + (pon & 0xFFFFu));
            }
            h2 m0 = ash2(di.x) * ash2(dj.x);         // v_pk_mul_f16
            h2 m1 = ash2(di.y) * ash2(dj.y);
            h2 m2 = ash2(di.z) * ash2(dj.z);
            h2 m3 = ash2(di.w) * ash2(dj.w);
            union { h2 hh[4]; f16x8 v; } u;
            u.hh[0] = m0; u.hh[1] = m1; u.hh[2] = m2; u.hh[3] = m3;
            f32x16 d = __builtin_amdgcn_mfma_f32_32x32x16_f16(wfrag, u.v,
                                                              cinit, 0, 0, 0);
            h2 c0 = relu2(cvt2(d[0], d[1]));
            h2 c1 = relu2(cvt2(d[2], d[3]));
            h2 c2 = relu2(cvt2(d[4], d[5]));
            h2 c3 = relu2(cvt2(d[6], d[7]));
            float sc = fdot2f(c0, hp0,
                       fdot2f(c1, hp1,
                       fdot2f(c2, hp2,
                       fdot2f(c3, hp3, 0.f))));      // v_dot2_f32_f16 x4
            sc += __shfl_xor(sc, 32);                // sum the two a-halves
            float w = __builtin_amdgcn_exp2f(sc);
            if (t == NT - 1) w = (n < PP - (NT - 1) * 32) ? w : 0.f;
            z  += w;
            aw  = fmaf(w, d[8], aw);   // d[8]: row16 (=bi.p) h=0, zero on h=1
            di = diN; dj = djN; pon = pon2;
        }

        // ---- final reduce: aw, z, fo in one shuffle block -----------------
        float fo = fcur * vcur;
        #pragma unroll
        for (int m = 1; m < 64; m <<= 1) {
            aw += __shfl_xor(aw, m);
            z  += __shfl_xor(z, m);
            fo += __shfl_xor(fo, m);
        }
        if (lane == 0) {
            // lane-sum aw counts each pair once; lane-sum z = 2*Z.
            float y = bias[0] + fo + 2.f * aw / z;
            out[s0 + s] = 1.f / (1.f + __expf(-y));
        }

        vcur = vnxt; fcur = fnxt;   // rotate per-sample state
    }
}

extern "C" void kernel_launch(void* const* d_in, const int* in_sizes, int n_in,
                              void* d_out, int out_size, void* d_ws, size_t ws_size,
                              hipStream_t stream) {
    const int*   fidx      = (const int*)  d_in[0];
    const float* fval      = (const float*)d_in[1];
    const float* fow       = (const float*)d_in[2];
    const float* emb_table = (const float*)d_in[3];
    const float* bias      = (const float*)d_in[4];
    const float* attn_w    = (const float*)d_in[5];
    const float* attn_b    = (const float*)d_in[6];
    const float* proj_h    = (const float*)d_in[7];
    const float* proj_p    = (const float*)d_in[8];
    float* out = (float*)d_out;

    afm_kernel<<<BB / (2 * SPW), 128, 0, stream>>>(fidx, fval, fow, emb_table,
                                                   bias, attn_w, attn_b,
                                                   proj_h, proj_p, out);
}

// Round 3
// 125.375 us; speedup vs baseline: 1.0450x; 1.0450x over previous
//
#include <hip/hip_runtime.h>
#include <hip/hip_fp16.h>
#include <math.h>

// AFM forward, FINAL (reverted to proven best: JSON 123.9-124.2us, kernel
// ~31.7us). One wave = one sample. Pooling folded INTO the MFMA via A-row 16
// = proj_p (D[16][n] = bi.p arrives in d[8] of h=0 lanes; h=1 lanes read
// zero-row 20). Zero barriers (same-wave LDS ordering); constexpr pair table
// preloaded to registers (6 dwordx4, L1); fp16 scaled rows in LDS (RBYTES=48
// pad); 1-tile-ahead ds_read prefetch; mfma_f32_32x32x16_f16 (K=16 exact);
// packed relu (v_pk_max_f16) + v_dot2_f32_f16 score; exp2 with h pre-scaled
// by log2(e); single 64-lane shuffle reduce of (aw, z, fo).
//
// Session laws (r6/r13/r15 + this session r1/r2): (1) launch_bounds must
// leave >=100 VGPR or the body spills catastrophically; (2) exactly ONE
// inlined tile-loop instance per kernel; (3) cross-sample gather/compute
// pipelining (global_load_lds DMA + cvt pass) is NEGATIVE at any occupancy
// (r1: +2.7us @4blk/CU, r2: +6.8us @iso-20-waves/CU) -- per-wave gather
// latency is already hidden by inter-wave TLP; the kernel sits at the DRAM
// random-64B-request envelope (~0.96M line requests, ~30 G req/s ~ 1.9 TB/s
// effective), so added LDS round-trips / fences are pure cost.

#define BB 8192
#define FF 39
#define PP 741
#define NT 24                 // 32-pair tiles per sample; tile 23 has 5 valid
#define RBYTES 48             // fp16 row stride: 32B data + 16B pad
#define SBYTES (FF * RBYTES)  // 1872 B per sample

typedef _Float16 f16x8 __attribute__((ext_vector_type(8)));
typedef _Float16 h2    __attribute__((ext_vector_type(2)));
typedef __fp16   hw2   __attribute__((ext_vector_type(2)));  // builtin ABI type
typedef float    f32x4  __attribute__((ext_vector_type(4)));
typedef float    f32x16 __attribute__((ext_vector_type(16)));

// static pair table, transposed: v[n][k] = byte offsets of pair p = k*32+n,
// packed (i*RBYTES)<<16 | (j*RBYTES). Dead slots (p>=741) stay 0 (masked).
struct alignas(16) PijT { unsigned v[32][NT]; };
static constexpr PijT make_pij() {
    PijT t{};
    int p = 0;
    for (int i = 0; i < FF; ++i)
        for (int j = i + 1; j < FF; ++j) {
            t.v[p & 31][p >> 5] =
                ((unsigned)(i * RBYTES) << 16) | (unsigned)(j * RBYTES);
            ++p;
        }
    return t;
}
__device__ constexpr PijT c_pij = make_pij();

static __device__ __forceinline__ h2 cvt2(float lo, float hi) {
    return __builtin_bit_cast(h2, __builtin_amdgcn_cvt_pkrtz(lo, hi));
}
static __device__ __forceinline__ h2 ash2(unsigned d) {
    return __builtin_bit_cast(h2, d);
}
static __device__ __forceinline__ float fdot2f(h2 a, h2 b, float c) {
    return __builtin_amdgcn_fdot2(__builtin_bit_cast(hw2, a),
                                  __builtin_bit_cast(hw2, b), c, false);
}
static __device__ __forceinline__ h2 relu2(h2 x) {
    const h2 zz = {(_Float16)0.f, (_Float16)0.f};
    return __builtin_elementwise_max(x, zz);   // v_pk_max_f16
}

__global__ __launch_bounds__(256, 5)
void afm_kernel(const int*   __restrict__ fidx,
                const float* __restrict__ fval,
                const float* __restrict__ fow,
                const float* __restrict__ emb,
                const float* __restrict__ bias,
                const float* __restrict__ aw_,   // [E=16][A=16] row-major
                const float* __restrict__ ab_,   // [16]
                const float* __restrict__ ph_,   // [16]
                const float* __restrict__ pp_,   // [16]
                float*       __restrict__ out)
{
    __shared__ __align__(16) unsigned char s_emb[4 * SBYTES];  // 7488 B

    const int tid  = threadIdx.x;
    const int wid  = tid >> 6;
    const int lane = tid & 63;
    const int n    = lane & 31;      // pair slot within tile
    const int h    = lane >> 5;      // e-half / k-half
    const int smp  = blockIdx.x * 4 + wid;

    // ---- per-wave: indices + values ----
    int ixr = 0; float vr = 0.f;
    if (lane < FF) {
        ixr = fidx[smp * FF + lane];
        vr  = fval[smp * FF + lane];
    }

    // ---- stage scaled rows as fp16 (78 half-row tasks, same wave) ----
    unsigned char* my = s_emb + wid * SBYTES;
    for (int u = lane; u < FF * 2; u += 64) {
        int row = u >> 1, hh = u & 1;
        int   ix = __shfl(ixr, row);
        float v  = __shfl(vr,  row);
        const float4* src = (const float4*)emb + (size_t)ix * 4 + hh * 2;
        float4 e0 = src[0], e1 = src[1];
        h2 a0 = cvt2(e0.x * v, e0.y * v);
        h2 a1 = cvt2(e0.z * v, e0.w * v);
        h2 a2 = cvt2(e1.x * v, e1.y * v);
        h2 a3 = cvt2(e1.z * v, e1.w * v);
        uint4 d = make_uint4(__builtin_bit_cast(unsigned, a0),
                             __builtin_bit_cast(unsigned, a1),
                             __builtin_bit_cast(unsigned, a2),
                             __builtin_bit_cast(unsigned, a3));
        *(uint4*)(my + row * RBYTES + hh * 16) = d;
    }

    // ---- first-order partial (reduced at the very end with aw,z) ----
    float fo = (lane < FF) ? fow[ixr] * vr : 0.f;

    // ---- constant fragments ----
    const float LOG2E = 1.44269504088896f;
    // packed h coefficients (pre-scaled by log2 e), matching D-reg pair order:
    // regs 0..3 -> a = 4h + r ; regs 4..7 -> a = 8 + 4h + r
    h2 hp0, hp1, hp2, hp3;
    {
        const f32x4 lo = ((const f32x4*)ph_)[h];
        const f32x4 hi = ((const f32x4*)ph_)[h + 2];
        hp0 = cvt2(lo[0] * LOG2E, lo[1] * LOG2E);
        hp1 = cvt2(lo[2] * LOG2E, lo[3] * LOG2E);
        hp2 = cvt2(hi[0] * LOG2E, hi[1] * LOG2E);
        hp3 = cvt2(hi[2] * LOG2E, hi[3] * LOG2E);
    }

    f32x16 cinit;                   // bias in rows a<16; rows >=16 zero
    {                               // (row 16 = proj_p row must have C=0)
        const f32x4 ab_lo = ((const f32x4*)ab_)[h];
        const f32x4 ab_hi = ((const f32x4*)ab_)[h + 2];
        cinit[0] = ab_lo[0]; cinit[1] = ab_lo[1];
        cinit[2] = ab_lo[2]; cinit[3] = ab_lo[3];
        cinit[4] = ab_hi[0]; cinit[5] = ab_hi[1];
        cinit[6] = ab_hi[2]; cinit[7] = ab_hi[3];
        #pragma unroll
        for (int r = 8; r < 16; ++r) cinit[r] = 0.f;
    }

    f16x8 wfrag;        // A: rows 0..15 = W^T, row 16 = proj_p, 17..31 zero
    {
        float t0 = 0.f, t1 = 0.f, t2 = 0.f, t3 = 0.f,
              t4 = 0.f, t5 = 0.f, t6 = 0.f, t7 = 0.f;
        if (n < 16) {
            const float* base = aw_ + (8 * h) * 16 + n;  // W[k=8h+j][m=n]
            t0 = base[0];   t1 = base[16];  t2 = base[32];  t3 = base[48];
            t4 = base[64];  t5 = base[80];  t6 = base[96];  t7 = base[112];
        } else if (n == 16) {
            const float* base = pp_ + 8 * h;             // p[k=8h+j]
            t0 = base[0]; t1 = base[1]; t2 = base[2]; t3 = base[3];
            t4 = base[4]; t5 = base[5]; t6 = base[6]; t7 = base[7];
        }
        union { h2 hh[4]; f16x8 v; } u;
        u.hh[0] = cvt2(t0, t1); u.hh[1] = cvt2(t2, t3);
        u.hh[2] = cvt2(t4, t5); u.hh[3] = cvt2(t6, t7);
        wfrag = u.v;
    }

    // ---- preload all 24 pair offsets into registers (L1, 6 dwordx4) ----
    unsigned po[NT];
    {
        const uint4* myp4 = (const uint4*)c_pij.v[n];
        #pragma unroll
        for (int g = 0; g < 6; ++g) {
            uint4 q = myp4[g];
            po[4 * g + 0] = q.x; po[4 * g + 1] = q.y;
            po[4 * g + 2] = q.z; po[4 * g + 3] = q.w;
        }
    }

    // ---- main loop: 24 tiles, software-pipelined LDS reads (1 tile ahead) --
    const unsigned char* bpre = my + h * 16;    // this lane's e-half
    float aw = 0.f;                             // sum_p w_p * (bi_p . p)
    float z  = 0.f;                             // sum_p w_p (x2 across halves)

    uint4 di = *(const uint4*)(bpre + (po[0] >> 16));
    uint4 dj = *(const uint4*)(bpre + (po[0] & 0xFFFFu));

    #pragma unroll
    for (int t = 0; t < NT; ++t) {
        uint4 diN = di, djN = dj;
        if (t + 1 < NT) {                        // compile-time under unroll
            diN = *(const uint4*)(bpre + (po[t + 1] >> 16));
            djN = *(const uint4*)(bpre + (po[t + 1] & 0xFFFFu));
        }
        h2 m0 = ash2(di.x) * ash2(dj.x);         // v_pk_mul_f16
        h2 m1 = ash2(di.y) * ash2(dj.y);
        h2 m2 = ash2(di.z) * ash2(dj.z);
        h2 m3 = ash2(di.w) * ash2(dj.w);
        union { h2 hh[4]; f16x8 v; } u;
        u.hh[0] = m0; u.hh[1] = m1; u.hh[2] = m2; u.hh[3] = m3;
        f32x16 d = __builtin_amdgcn_mfma_f32_32x32x16_f16(wfrag, u.v,
                                                          cinit, 0, 0, 0);
        h2 c0 = relu2(cvt2(d[0], d[1]));
        h2 c1 = relu2(cvt2(d[2], d[3]));
        h2 c2 = relu2(cvt2(d[4], d[5]));
        h2 c3 = relu2(cvt2(d[6], d[7]));
        float s = fdot2f(c0, hp0,
                  fdot2f(c1, hp1,
                  fdot2f(c2, hp2,
                  fdot2f(c3, hp3, 0.f))));       // v_dot2_f32_f16 x4
        s += __shfl_xor(s, 32);                  // sum the two a-halves
        float w = __builtin_amdgcn_exp2f(s);
        if (t == NT - 1) w = (n < PP - (NT - 1) * 32) ? w : 0.f;
        z  += w;
        aw  = fmaf(w, d[8], aw);   // d[8]: row16 (=bi.p) on h=0, zero on h=1
        di = diN; dj = djN;
    }

    // ---- final reduce: aw, z, fo in one shuffle block ----
    #pragma unroll
    for (int m = 1; m < 64; m <<= 1) {
        aw += __shfl_xor(aw, m);
        z  += __shfl_xor(z, m);
        fo += __shfl_xor(fo, m);
    }
    if (lane == 0) {
        // lane-sum aw counts each pair once; lane-sum z = 2*Z.
        float y = bias[0] + fo + 2.f * aw / z;
        out[smp] = 1.f / (1.f + __expf(-y));
    }
}

extern "C" void kernel_launch(void* const* d_in, const int* in_sizes, int n_in,
                              void* d_out, int out_size, void* d_ws, size_t ws_size,
                              hipStream_t stream) {
    const int*   fidx      = (const int*)  d_in[0];
    const float* fval      = (const float*)d_in[1];
    const float* fow       = (const float*)d_in[2];
    const float* emb_table = (const float*)d_in[3];
    const float* bias      = (const float*)d_in[4];
    const float* attn_w    = (const float*)d_in[5];
    const float* attn_b    = (const float*)d_in[6];
    const float* proj_h    = (const float*)d_in[7];
    const float* proj_p    = (const float*)d_in[8];
    float* out = (float*)d_out;

    afm_kernel<<<BB / 4, 256, 0, stream>>>(fidx, fval, fow, emb_table, bias,
                                           attn_w, attn_b, proj_h, proj_p, out);
}